// Round 3
// baseline (192.949 us; speedup 1.0000x reference)
//
#include <hip/hip_runtime.h>
#include <hip/hip_cooperative_groups.h>

namespace cg = cooperative_groups;

// SIMDIS: mean cosine similarity -> bottom-100 argsort -> gather.
// mean_sim_i = (x_i . s) / (n_i * N), s = sum_j x_j / n_j  -> O(N*D).
// Single cooperative kernel: norms+colsum | score | select | sort+gather,
// separated by grid.sync() instead of kernel launches.
// s accumulated via deterministic i64 fixed-point atomics (scale 2^44) into
// 8 replicas (contention /8); integer adds commute -> bit-exact replay.

#define N 8192
#define D 512
#define K 100
#define NBLK 256
#define RPB 32            // rows per block = N / NBLK

typedef unsigned long long u64;
typedef unsigned int u32;

#define SCALE 17592186044416.0          // 2^44
#define INV_SCALE (1.0 / 17592186044416.0)

__device__ __forceinline__ u32 f32_sortable(float f) {
    u32 u = __float_as_uint(f);
    return (u & 0x80000000u) ? ~u : (u | 0x80000000u);
}

// Bitonic sort of 1024 u64 keys in LDS, ascending; 256 threads, 4 elems each.
// Per round, pairs (e, e^j) are disjoint and touched only by the owner of the
// lower index -> race-free with one barrier per round.
__device__ __forceinline__ void bitonic1024(u64* lds) {
    int t = threadIdx.x;
    for (int k = 2; k <= 1024; k <<= 1) {
        for (int j = k >> 1; j > 0; j >>= 1) {
#pragma unroll
            for (int q = 0; q < 4; ++q) {
                int e = t + q * 256;
                int ixj = e ^ j;
                if (ixj > e) {
                    u64 a = lds[e], b = lds[ixj];
                    bool up = ((e & k) == 0);
                    if ((a > b) == up) { lds[e] = b; lds[ixj] = a; }
                }
            }
            __syncthreads();
        }
    }
}

__global__ __launch_bounds__(256) void simdis_k(const float* __restrict__ x,
                                                u64* __restrict__ s_rep,   // [8][D]
                                                u64* __restrict__ keys,    // [N]
                                                u64* __restrict__ cand,    // [1024]
                                                float* __restrict__ out) {
    cg::grid_group grid = cg::this_grid();

    __shared__ double inv_loc[RPB];
    __shared__ double s_lds[D];
    __shared__ u64 sort_lds[1024];
    __shared__ int sel[K];

    int t = threadIdx.x;
    int lane = t & 63, wave = t >> 6;
    int b = blockIdx.x;
    int row0 = b * RPB;

    // ---- Phase 1a: norms (wave per row, 8 rows per wave) ----
    for (int i = 0; i < RPB / 4; ++i) {
        int li = wave * (RPB / 4) + i;
        int r = row0 + li;
        const float4* xr = (const float4*)(x + (size_t)r * D);
        float4 a = xr[lane];
        float4 c = xr[lane + 64];
        double sm = (double)a.x * a.x + (double)a.y * a.y + (double)a.z * a.z + (double)a.w * a.w
                  + (double)c.x * c.x + (double)c.y * c.y + (double)c.z * c.z + (double)c.w * c.w;
        for (int off = 32; off > 0; off >>= 1) sm += __shfl_down(sm, off);
        if (lane == 0) inv_loc[li] = 1.0 / sqrt(sm);
    }
    __syncthreads();

    // ---- Phase 1b: fixed-point column sums into replica (blk & 7) ----
    {
        double a0 = 0.0, a1 = 0.0;
        for (int r = 0; r < RPB; ++r) {
            double w = inv_loc[r];
            const float* xr = x + (size_t)(row0 + r) * D;   // L1/L2-hot
            a0 += (double)xr[t] * w;
            a1 += (double)xr[t + 256] * w;
        }
        u64* rep = s_rep + (size_t)(b & 7) * D;
        atomicAdd(rep + t,       (u64)(long long)__double2ll_rn(a0 * SCALE));
        atomicAdd(rep + t + 256, (u64)(long long)__double2ll_rn(a1 * SCALE));
    }

    grid.sync();

    // ---- Phase 2: reduce replicas -> s in LDS, score own 32 rows ----
    {
        u64 v0 = 0, v1 = 0;
        for (int rp = 0; rp < 8; ++rp) {
            v0 += s_rep[(size_t)rp * D + t];
            v1 += s_rep[(size_t)rp * D + t + 256];
        }
        s_lds[t]       = (double)(long long)v0 * INV_SCALE;
        s_lds[t + 256] = (double)(long long)v1 * INV_SCALE;
    }
    __syncthreads();

    for (int i = 0; i < RPB / 4; ++i) {
        int li = wave * (RPB / 4) + i;
        int r = row0 + li;
        const float4* xr = (const float4*)(x + (size_t)r * D);
        float4 a = xr[lane];
        float4 c = xr[lane + 64];
        int c0 = lane * 4, c1 = (lane + 64) * 4;
        double acc = (double)a.x * s_lds[c0]     + (double)a.y * s_lds[c0 + 1]
                   + (double)a.z * s_lds[c0 + 2] + (double)a.w * s_lds[c0 + 3]
                   + (double)c.x * s_lds[c1]     + (double)c.y * s_lds[c1 + 1]
                   + (double)c.z * s_lds[c1 + 2] + (double)c.w * s_lds[c1 + 3];
        for (int off = 32; off > 0; off >>= 1) acc += __shfl_down(acc, off);
        if (lane == 0) {
            float sc = (float)(acc * inv_loc[li]);
            keys[r] = ((u64)f32_sortable(sc) << 32) | (u32)r;
        }
    }

    grid.sync();

    // ---- Phase 3: blocks 0-7 sort 1024 keys, keep bottom 128 ----
    // Any global bottom-100 element has rank < 100 < 128 within its block.
    if (b < 8) {
#pragma unroll
        for (int q = 0; q < 4; ++q)
            sort_lds[t + q * 256] = keys[b * 1024 + t + q * 256];
        __syncthreads();
        bitonic1024(sort_lds);
        if (t < 128) cand[b * 128 + t] = sort_lds[t];
    }

    grid.sync();

    // ---- Phase 4: block 0 sorts candidates, writes indices, gathers ----
    if (b == 0) {
#pragma unroll
        for (int q = 0; q < 4; ++q)
            sort_lds[t + q * 256] = cand[t + q * 256];
        __syncthreads();
        bitonic1024(sort_lds);
        if (t < K) {
            int idx = (int)(u32)(sort_lds[t] & 0xffffffffu);
            sel[t] = idx;
            out[(size_t)K * D + t] = (float)idx;   // indices exact in f32
        }
        __syncthreads();
        const float4* xv = (const float4*)x;
        float4* ov = (float4*)out;
        for (int i = t; i < K * (D / 4); i += 256) {
            int g = i >> 7, e = i & 127;
            ov[(size_t)g * (D / 4) + e] = xv[(size_t)sel[g] * (D / 4) + e];
        }
    }
}

extern "C" void kernel_launch(void* const* d_in, const int* in_sizes, int n_in,
                              void* d_out, int out_size, void* d_ws, size_t ws_size,
                              hipStream_t stream) {
    const float* x = (const float*)d_in[0];
    float* out = (float*)d_out;               // [K*D gathered rows][K indices]

    char* ws = (char*)d_ws;
    u64* s_rep = (u64*)(ws);                  // 8 * 512 * 8 = 32768
    u64* keys  = (u64*)(ws + 32768);          // 8192 * 8   = 65536
    u64* cand  = (u64*)(ws + 98304);          // 1024 * 8   =  8192

    hipMemsetAsync(s_rep, 0, 8 * D * sizeof(u64), stream);

    void* args[] = { (void*)&x, (void*)&s_rep, (void*)&keys, (void*)&cand, (void*)&out };
    hipLaunchCooperativeKernel((const void*)simdis_k, dim3(NBLK), dim3(256),
                               args, 0, stream);
}

// Round 4
// 92.515 us; speedup vs baseline: 2.0856x; 2.0856x over previous
//
#include <hip/hip_runtime.h>

// SIMDIS: mean cosine similarity -> bottom-100 argsort -> gather.
// mean_sim_i = (x_i . s) / (n_i * N), s = sum_j x_j / n_j  -> O(N*D), 2 passes.
// s via deterministic i64 fixed-point atomics (scale 2^44, 4 replicas):
// integer adds commute -> bit-exact across replays; quantization ~2^-38 vs
// rank-100 score gaps ~2e-2. Selection: exact 3-level histogram radix-select
// (one block) instead of big bitonic sorts; final order = ascending u64
// (score, index) = numpy stable ascending argsort.

#define N 8192
#define D 512
#define K 100
#define REP 4
#define ROWS_PER_BLK 16   // pass1: 512 blocks x 16 rows

typedef unsigned long long u64;
typedef unsigned int u32;

#define SCALE 17592186044416.0          // 2^44
#define INV_SCALE (1.0 / 17592186044416.0)

__device__ __forceinline__ u32 f32_sortable(float f) {
    u32 u = __float_as_uint(f);
    return (u & 0x80000000u) ? ~u : (u | 0x80000000u);
}

// ---------------- pass 1: norms + fixed-point column sums ----------------
__global__ __launch_bounds__(256) void pass1_k(const float* __restrict__ x,
                                               double* __restrict__ inv_n,
                                               u64* __restrict__ s_rep) {
    __shared__ double inv_loc[ROWS_PER_BLK];
    int t = threadIdx.x;
    int lane = t & 63, wave = t >> 6;
    int b = blockIdx.x;
    int row0 = b * ROWS_PER_BLK;

    // wave per row, 4 rows per wave
    for (int i = 0; i < ROWS_PER_BLK / 4; ++i) {
        int li = wave * (ROWS_PER_BLK / 4) + i;
        int r = row0 + li;
        const float4* xr = (const float4*)(x + (size_t)r * D);
        float4 a = xr[lane];
        float4 c = xr[lane + 64];
        double sm = (double)a.x * a.x + (double)a.y * a.y + (double)a.z * a.z + (double)a.w * a.w
                  + (double)c.x * c.x + (double)c.y * c.y + (double)c.z * c.z + (double)c.w * c.w;
        for (int off = 32; off > 0; off >>= 1) sm += __shfl_down(sm, off);
        if (lane == 0) {
            double v = 1.0 / sqrt(sm);
            inv_n[r] = v;
            inv_loc[li] = v;
        }
    }
    __syncthreads();

    // thread t accumulates cols t, t+256 over this block's rows (L1/L2-hot)
    double a0 = 0.0, a1 = 0.0;
    for (int r = 0; r < ROWS_PER_BLK; ++r) {
        double w = inv_loc[r];
        const float* xr = x + (size_t)(row0 + r) * D;
        a0 += (double)xr[t] * w;
        a1 += (double)xr[t + 256] * w;
    }
    u64* rep = s_rep + (size_t)(b & (REP - 1)) * D;
    atomicAdd(rep + t,       (u64)(long long)__double2ll_rn(a0 * SCALE));
    atomicAdd(rep + t + 256, (u64)(long long)__double2ll_rn(a1 * SCALE));
}

// ---------------- pass 2: scores -> sortable u64 keys ----------------
__global__ __launch_bounds__(256) void score_k(const float* __restrict__ x,
                                               const double* __restrict__ inv_n,
                                               const u64* __restrict__ s_rep,
                                               u64* __restrict__ keys) {
    __shared__ double s_lds[D];
    int t = threadIdx.x;
    int lane = t & 63, wave = t >> 6;

    u64 v0 = 0, v1 = 0;
    for (int rp = 0; rp < REP; ++rp) {
        v0 += s_rep[(size_t)rp * D + t];
        v1 += s_rep[(size_t)rp * D + t + 256];
    }
    s_lds[t]       = (double)(long long)v0 * INV_SCALE;
    s_lds[t + 256] = (double)(long long)v1 * INV_SCALE;
    __syncthreads();

    int row = (blockIdx.x << 2) + wave;
    const float4* xr = (const float4*)(x + (size_t)row * D);
    float4 a = xr[lane];
    float4 c = xr[lane + 64];
    int c0 = lane * 4, c1 = (lane + 64) * 4;
    double acc = (double)a.x * s_lds[c0]     + (double)a.y * s_lds[c0 + 1]
               + (double)a.z * s_lds[c0 + 2] + (double)a.w * s_lds[c0 + 3]
               + (double)c.x * s_lds[c1]     + (double)c.y * s_lds[c1 + 1]
               + (double)c.z * s_lds[c1 + 2] + (double)c.w * s_lds[c1 + 3];
    for (int off = 32; off > 0; off >>= 1) acc += __shfl_down(acc, off);
    if (lane == 0) {
        float sc = (float)(acc * inv_n[row]);
        keys[row] = ((u64)f32_sortable(sc) << 32) | (u32)row;
    }
}

// ---------------- selection: exact histogram radix-select ----------------
// Executed by wave 0 only. Finds first bin where cumulative count >= need;
// writes bin -> ctrl[0], strictly-below count -> ctrl[1].
__device__ __forceinline__ void find_crossing(const u32* hist, int nbins,
                                              u32 need, u32* ctrl) {
    int lane = threadIdx.x;   // 0..63
    u32 carry = 0;
    for (int it = 0; it < nbins / 64; ++it) {
        u32 h = hist[it * 64 + lane];
        u32 v = h;
        for (int off = 1; off < 64; off <<= 1) {
            u32 n = __shfl_up(v, off);
            if (lane >= off) v += n;
        }
        u32 incl = carry + v;
        u64 m = __ballot(incl >= need);
        if (m) {
            int l = __ffsll((unsigned long long)m) - 1;
            if (lane == l) { ctrl[0] = (u32)(it * 64 + l); ctrl[1] = incl - h; }
            return;
        }
        carry += __shfl(v, 63);
    }
    if (lane == 0) { ctrl[0] = (u32)(nbins - 1); ctrl[1] = 0; }
}

__global__ __launch_bounds__(1024) void selgather_k(const u64* __restrict__ keys,
                                                    const float* __restrict__ x,
                                                    float* __restrict__ out) {
    __shared__ u64 keyb[N];        // 64 KB
    __shared__ u32 hist[4096];     // 16 KB
    __shared__ u64 cand[256];
    __shared__ u32 ctrl[4];        // [0]=bin [1]=below [2]=n_cand
    int t = threadIdx.x;

#pragma unroll
    for (int q = 0; q < 8; ++q) keyb[q * 1024 + t] = keys[q * 1024 + t];

    u32 c_acc = 0, B0, B1, B2;

    // level 0: top 12 bits of score
    for (int i = t; i < 4096; i += 1024) hist[i] = 0;
    __syncthreads();
#pragma unroll
    for (int q = 0; q < 8; ++q) {
        u32 sc = (u32)(keyb[q * 1024 + t] >> 32);
        atomicAdd(&hist[sc >> 20], 1u);
    }
    __syncthreads();
    if (t < 64) find_crossing(hist, 4096, 100u, ctrl);
    __syncthreads();
    B0 = ctrl[0]; c_acc = ctrl[1];
    __syncthreads();

    // level 1: middle 12 bits, within bin B0
    for (int i = t; i < 4096; i += 1024) hist[i] = 0;
    __syncthreads();
#pragma unroll
    for (int q = 0; q < 8; ++q) {
        u32 sc = (u32)(keyb[q * 1024 + t] >> 32);
        if ((sc >> 20) == B0) atomicAdd(&hist[(sc >> 8) & 0xFFFu], 1u);
    }
    __syncthreads();
    if (t < 64) find_crossing(hist, 4096, 100u - c_acc, ctrl);
    __syncthreads();
    B1 = ctrl[0]; c_acc += ctrl[1];
    __syncthreads();

    // level 2: low 8 bits, within (B0, B1)
    for (int i = t; i < 256; i += 1024) hist[i] = 0;
    __syncthreads();
#pragma unroll
    for (int q = 0; q < 8; ++q) {
        u32 sc = (u32)(keyb[q * 1024 + t] >> 32);
        if ((sc >> 20) == B0 && ((sc >> 8) & 0xFFFu) == B1)
            atomicAdd(&hist[sc & 0xFFu], 1u);
    }
    __syncthreads();
    if (t < 64) find_crossing(hist, 256, 100u - c_acc, ctrl);
    __syncthreads();
    B2 = ctrl[0];
    u32 T = (B0 << 20) | (B1 << 8) | B2;   // exact 100th-smallest score bits

    // collect all keys with score <= T  (count = c_lt + ties, c_lt <= 99)
    if (t == 0) ctrl[2] = 0;
    __syncthreads();
#pragma unroll
    for (int q = 0; q < 8; ++q) {
        u64 k = keyb[q * 1024 + t];
        u32 sc = (u32)(k >> 32);
        if (sc <= T) {
            u32 pos = atomicAdd(&ctrl[2], 1u);
            if (pos < 256) cand[pos] = k;
        }
    }
    __syncthreads();
    u32 nc = ctrl[2];
    for (int i = t; i < 256; i += 1024)
        if ((u32)i >= nc) cand[i] = ~0ull;
    __syncthreads();

    // bitonic sort 256 candidates ascending (u64 = (score, index))
    for (int k2 = 2; k2 <= 256; k2 <<= 1) {
        for (int j = k2 >> 1; j > 0; j >>= 1) {
            if (t < 256) {
                int ixj = t ^ j;
                if (ixj > t) {
                    u64 a = cand[t], b = cand[ixj];
                    bool up = ((t & k2) == 0);
                    if ((a > b) == up) { cand[t] = b; cand[ixj] = a; }
                }
            }
            __syncthreads();
        }
    }

    if (t < K)
        out[(size_t)K * D + t] = (float)(u32)(cand[t] & 0xffffffffu);
    __syncthreads();

    // gather the 100 rows (bit-exact copies)
    const float4* xv = (const float4*)x;
    float4* ov = (float4*)out;
    for (int i = t; i < K * (D / 4); i += 1024) {
        int g = i >> 7, e = i & 127;
        int idx = (int)(u32)(cand[g] & 0xffffffffu);
        ov[(size_t)g * (D / 4) + e] = xv[(size_t)idx * (D / 4) + e];
    }
}

extern "C" void kernel_launch(void* const* d_in, const int* in_sizes, int n_in,
                              void* d_out, int out_size, void* d_ws, size_t ws_size,
                              hipStream_t stream) {
    const float* x = (const float*)d_in[0];
    float* out = (float*)d_out;               // [K*D gathered rows][K indices]

    char* ws = (char*)d_ws;
    double* inv_n = (double*)(ws);            // 8192 * 8      = 65536
    u64*    s_rep = (u64*)   (ws + 65536);    // 4 * 512 * 8   = 16384
    u64*    keys  = (u64*)   (ws + 81920);    // 8192 * 8      = 65536

    hipMemsetAsync(s_rep, 0, REP * D * sizeof(u64), stream);
    pass1_k    <<<N / ROWS_PER_BLK, 256, 0, stream>>>(x, inv_n, s_rep);
    score_k    <<<N / 4, 256, 0, stream>>>(x, inv_n, s_rep, keys);
    selgather_k<<<1, 1024, 0, stream>>>(keys, x, out);
}